// Round 7
// baseline (1188.417 us; speedup 1.0000x reference)
//
#include <hip/hip_runtime.h>

// TAM fused kernel round 7: R6 structure + software pipeline across samples.
// Persistent blocks process SPB=8 consecutive samples. Next sample is
// prefetched into REGISTERS while the current one is computed/stored; all
// in-loop barriers are raw s_barrier with lgkm-only waits (no vmcnt(0)
// drains -> prefetch loads stay in flight across barriers, T3/T4 style).
// NT stores (R6 win: clean 440MB writeback). Plain loads (L3 retention).
// C=12, T=10, H*W=28, K=3.

#define CC 12
#define TT 10
#define SAMPLE 3360
#define SAMPLE4 840
#define EPSF 1e-5f
#define SPB 8

typedef float f4 __attribute__((ext_vector_type(4)));

#define FENCE() __builtin_amdgcn_sched_barrier(0)
// Raw block barrier: LDS-producer visibility only (lgkmcnt), never vmcnt.
#define BLOCK_SYNC() do { asm volatile("s_waitcnt lgkmcnt(0)" ::: "memory"); \
    FENCE(); __builtin_amdgcn_s_barrier(); FENCE(); } while (0)

__global__ __launch_bounds__(256, 8) void tam_kernel(
    const float* __restrict__ x,
    const float* __restrict__ w_g1,
    const float* __restrict__ g1_gamma, const float* __restrict__ g1_beta,
    const float* __restrict__ g1_mean,  const float* __restrict__ g1_var,
    const float* __restrict__ w_g2,
    const float* __restrict__ w_l1,
    const float* __restrict__ l1_gamma, const float* __restrict__ l1_beta,
    const float* __restrict__ l1_mean,  const float* __restrict__ l1_var,
    const float* __restrict__ w_l2,
    float* __restrict__ out, int n_total)
{
    __shared__ f4    sx4[SAMPLE4];   // current sample, input order [c][t][s4]
    __shared__ float spool[120];     // pooled[c][t]
    __shared__ float sz[240];        // G hidden
    __shared__ float sa1[30];        // L hidden [m][t]
    __shared__ float skern[36];      // k0[12] k1[12] k2[12]
    __shared__ float sact[120];      // sigmoid gate [c][t]
    __shared__ float wg1s[200], wg2s[60], wl1s[108], wl2s[36];
    __shared__ float gs[20], gb[20], lsc[3], lbi[3];

    const int tid = threadIdx.x;

    // ---- one-time weight staging + BN folding (before any x loads, so the
    // __syncthreads vmcnt drain costs nothing) ----
    for (int i = tid; i < 200; i += 256) wg1s[i] = w_g1[i];
    if (tid < 60)  wg2s[tid] = w_g2[tid];
    if (tid < 108) wl1s[tid] = w_l1[tid];
    if (tid < 36)  wl2s[tid] = w_l2[tid];
    if (tid < 20) {
        const float s = rsqrtf(g1_var[tid] + EPSF) * g1_gamma[tid];
        gs[tid] = s; gb[tid] = g1_beta[tid] - g1_mean[tid] * s;
    } else if (tid < 23) {
        const int m = tid - 20;
        const float s = rsqrtf(l1_var[m] + EPSF) * l1_gamma[m];
        lsc[m] = s; lbi[m] = l1_beta[m] - l1_mean[m] * s;
    }
    __syncthreads();

    const int n0 = blockIdx.x * SPB;
    f4 r[4];

    // ---- prologue: stage sample n0 (regs -> LDS) ----
    {
        const f4* xg = reinterpret_cast<const f4*>(x + (size_t)n0 * SAMPLE);
        #pragma unroll
        for (int k = 0; k < 4; ++k) {
            const int v = tid + k * 256;
            if (v < SAMPLE4) r[k] = xg[v];
        }
        #pragma unroll
        for (int k = 0; k < 4; ++k) {
            const int v = tid + k * 256;
            if (v < SAMPLE4) sx4[v] = r[k];
        }
    }
    BLOCK_SYNC();

    for (int s = 0; s < SPB; ++s) {
        const int n = n0 + s;
        if (n >= n_total) break;                    // block-uniform
        const bool pf = (s + 1 < SPB) && (n + 1 < n_total);

        // ---- 1. prefetch next sample into regs (stays in flight through
        //         all barriers below; compiler inserts counted vmcnt only
        //         right before the ds_write at step 6) ----
        if (pf) {
            const f4* xg = reinterpret_cast<const f4*>(x + (size_t)(n + 1) * SAMPLE);
            #pragma unroll
            for (int k = 0; k < 4; ++k) {
                const int v = tid + k * 256;
                if (v < SAMPLE4) r[k] = xg[v];
            }
        }

        // ---- 2. spatial mean -> spool (120 threads, 7 f4 each) ----
        if (tid < 120) {
            const f4* rp = sx4 + tid * 7;
            f4 a = rp[0];
            #pragma unroll
            for (int i = 1; i < 7; ++i) a += rp[i];
            spool[tid] = (a.x + a.y + a.z + a.w) * (1.0f / 28.0f);
        }
        BLOCK_SYNC();

        // ---- 3. G hidden (0..239) + L conv1 (240..269) ----
        for (int task = tid; task < 270; task += 256) {
            if (task < 240) {
                const int c = task / 20, j = task % 20;
                float acc = 0.f;
                #pragma unroll
                for (int t = 0; t < TT; ++t)
                    acc += spool[c * TT + t] * wg1s[j * TT + t];
                sz[task] = fmaxf(gs[j] * acc + gb[j], 0.f);
            } else {
                const int e = task - 240;
                const int m = e / TT, t = e % TT;
                float acc = 0.f;
                #pragma unroll
                for (int c = 0; c < CC; ++c) {
                    #pragma unroll
                    for (int k = 0; k < 3; ++k) {
                        const int t2 = t + k - 1;
                        if (t2 >= 0 && t2 < TT)
                            acc += spool[c * TT + t2] * wl1s[(m * CC + c) * 3 + k];
                    }
                }
                sa1[e] = fmaxf(lsc[m] * acc + lbi[m], 0.f);
            }
        }
        BLOCK_SYNC();

        // ---- 4. G softmax (12 lanes) + L conv2+sigmoid (120 lanes) ----
        if (tid < CC) {
            const int c = tid;
            float sc0 = 0.f, sc1 = 0.f, sc2 = 0.f;
            #pragma unroll
            for (int j = 0; j < 20; ++j) {
                const float zj = sz[c * 20 + j];
                sc0 += zj * wg2s[j];
                sc1 += zj * wg2s[20 + j];
                sc2 += zj * wg2s[40 + j];
            }
            const float mx = fmaxf(sc0, fmaxf(sc1, sc2));
            const float e0 = __expf(sc0 - mx), e1 = __expf(sc1 - mx), e2 = __expf(sc2 - mx);
            const float ri = 1.0f / (e0 + e1 + e2);
            skern[c]      = e0 * ri;
            skern[12 + c] = e1 * ri;
            skern[24 + c] = e2 * ri;
        }
        if (tid >= 64 && tid < 64 + 120) {
            const int idx = tid - 64;
            const int c = idx / TT, t = idx % TT;
            float acc = 0.f;
            #pragma unroll
            for (int m = 0; m < 3; ++m) acc += sa1[m * TT + t] * wl2s[c * 3 + m];
            sact[idx] = 1.0f / (1.0f + __expf(-acc));
        }
        BLOCK_SYNC();

        // ---- 5. apply: gated 3-tap conv from LDS, transposed NT store ----
        f4* og = reinterpret_cast<f4*>(out + (size_t)n * SAMPLE);
        #pragma unroll
        for (int k = 0; k < 4; ++k) {
            const int v = tid + k * 256;
            if (v < SAMPLE4) {
                const int t   = v / 84;
                const int rem = v % 84;
                const int c   = rem / 7;
                const int s4  = rem % 7;
                const int base = c * 70 + s4;
                const float k0 = skern[c];
                const float k1 = skern[12 + c];
                const float k2 = skern[24 + c];
                f4 acc = (k1 * sact[c * TT + t]) * sx4[base + t * 7];
                if (t > 0)
                    acc += (k0 * sact[c * TT + t - 1]) * sx4[base + (t - 1) * 7];
                if (t < TT - 1)
                    acc += (k2 * sact[c * TT + t + 1]) * sx4[base + (t + 1) * 7];
                __builtin_nontemporal_store(acc, og + v);
            }
        }

        // ---- 6. rotate: all waves done reading sx4, then overwrite with
        //         prefetched regs (compiler emits counted vmcnt here) ----
        BLOCK_SYNC();
        if (pf) {
            #pragma unroll
            for (int k = 0; k < 4; ++k) {
                const int v = tid + k * 256;
                if (v < SAMPLE4) sx4[v] = r[k];
            }
            BLOCK_SYNC();
        }
    }
}

extern "C" void kernel_launch(void* const* d_in, const int* in_sizes, int n_in,
                              void* d_out, int out_size, void* d_ws, size_t ws_size,
                              hipStream_t stream) {
    (void)n_in; (void)out_size; (void)d_ws; (void)ws_size;
    const float* x        = (const float*)d_in[0];
    const float* w_g1     = (const float*)d_in[1];
    const float* g1_gamma = (const float*)d_in[2];
    const float* g1_beta  = (const float*)d_in[3];
    const float* g1_mean  = (const float*)d_in[4];
    const float* g1_var   = (const float*)d_in[5];
    const float* w_g2     = (const float*)d_in[6];
    const float* w_l1     = (const float*)d_in[7];
    const float* l1_gamma = (const float*)d_in[8];
    const float* l1_beta  = (const float*)d_in[9];
    const float* l1_mean  = (const float*)d_in[10];
    const float* l1_var   = (const float*)d_in[11];
    const float* w_l2     = (const float*)d_in[12];
    float* out = (float*)d_out;

    const int n_total = in_sizes[0] / SAMPLE;              // 32768
    const int blocks  = (n_total + SPB - 1) / SPB;         // 4096
    tam_kernel<<<blocks, 256, 0, stream>>>(
        x, w_g1, g1_gamma, g1_beta, g1_mean, g1_var, w_g2,
        w_l1, l1_gamma, l1_beta, l1_mean, l1_var, w_l2, out, n_total);
}

// Round 8
// 235.727 us; speedup vs baseline: 5.0415x; 5.0415x over previous
//
#include <hip/hip_runtime.h>

// TAM fused kernel round 8: R7 pipeline, VGPR cap removed.
// R7's failure was __launch_bounds__(256,8) -> 32 VGPR cap -> r[4] prefetch
// spilled to scratch (WRITE 2.65GB, FETCH 952MB, dur 1188us). Same structure
// with default launch bounds: persistent blocks, SPB=8 samples, next sample
// prefetched into registers while current is computed; in-loop barriers are
// raw s_barrier + lgkmcnt-only waits so prefetch loads stay in flight
// (counted vmcnt is compiler-inserted only at the rotate ds_write).
// NT stores (R6 win). Plain loads (L3 retention). C=12,T=10,HW=28,K=3.

#define CC 12
#define TT 10
#define SAMPLE 3360
#define SAMPLE4 840
#define EPSF 1e-5f
#define SPB 8

typedef float f4 __attribute__((ext_vector_type(4)));

#define FENCE() __builtin_amdgcn_sched_barrier(0)
// Raw block barrier: LDS-producer visibility only (lgkmcnt), never vmcnt.
#define BLOCK_SYNC() do { asm volatile("s_waitcnt lgkmcnt(0)" ::: "memory"); \
    FENCE(); __builtin_amdgcn_s_barrier(); FENCE(); } while (0)

__global__ __launch_bounds__(256) void tam_kernel(
    const float* __restrict__ x,
    const float* __restrict__ w_g1,
    const float* __restrict__ g1_gamma, const float* __restrict__ g1_beta,
    const float* __restrict__ g1_mean,  const float* __restrict__ g1_var,
    const float* __restrict__ w_g2,
    const float* __restrict__ w_l1,
    const float* __restrict__ l1_gamma, const float* __restrict__ l1_beta,
    const float* __restrict__ l1_mean,  const float* __restrict__ l1_var,
    const float* __restrict__ w_l2,
    float* __restrict__ out, int n_total)
{
    __shared__ f4    sx4[SAMPLE4];   // current sample, input order [c][t][s4]
    __shared__ float spool[120];     // pooled[c][t]
    __shared__ float sz[240];        // G hidden
    __shared__ float sa1[30];        // L hidden [m][t]
    __shared__ float skern[36];      // k0[12] k1[12] k2[12]
    __shared__ float sact[120];      // sigmoid gate [c][t]
    __shared__ float wg1s[200], wg2s[60], wl1s[108], wl2s[36];
    __shared__ float gs[20], gb[20], lsc[3], lbi[3];

    const int tid = threadIdx.x;

    // ---- one-time weight staging + BN folding ----
    for (int i = tid; i < 200; i += 256) wg1s[i] = w_g1[i];
    if (tid < 60)  wg2s[tid] = w_g2[tid];
    if (tid < 108) wl1s[tid] = w_l1[tid];
    if (tid < 36)  wl2s[tid] = w_l2[tid];
    if (tid < 20) {
        const float s = rsqrtf(g1_var[tid] + EPSF) * g1_gamma[tid];
        gs[tid] = s; gb[tid] = g1_beta[tid] - g1_mean[tid] * s;
    } else if (tid < 23) {
        const int m = tid - 20;
        const float s = rsqrtf(l1_var[m] + EPSF) * l1_gamma[m];
        lsc[m] = s; lbi[m] = l1_beta[m] - l1_mean[m] * s;
    }
    __syncthreads();

    const int n0 = blockIdx.x * SPB;
    f4 r[4];

    // ---- prologue: stage sample n0 (regs -> LDS) ----
    {
        const f4* xg = reinterpret_cast<const f4*>(x + (size_t)n0 * SAMPLE);
        #pragma unroll
        for (int k = 0; k < 4; ++k) {
            const int v = tid + k * 256;
            if (v < SAMPLE4) r[k] = xg[v];
        }
        #pragma unroll
        for (int k = 0; k < 4; ++k) {
            const int v = tid + k * 256;
            if (v < SAMPLE4) sx4[v] = r[k];
        }
    }
    BLOCK_SYNC();

    for (int s = 0; s < SPB; ++s) {
        const int n = n0 + s;
        if (n >= n_total) break;                    // block-uniform
        const bool pf = (s + 1 < SPB) && (n + 1 < n_total);

        // ---- 1. prefetch next sample into regs (in flight through all
        //         barriers below; counted vmcnt only at step 6 ds_write) ----
        if (pf) {
            const f4* xg = reinterpret_cast<const f4*>(x + (size_t)(n + 1) * SAMPLE);
            #pragma unroll
            for (int k = 0; k < 4; ++k) {
                const int v = tid + k * 256;
                if (v < SAMPLE4) r[k] = xg[v];
            }
        }

        // ---- 2. spatial mean -> spool (120 threads, 7 f4 each) ----
        if (tid < 120) {
            const f4* rp = sx4 + tid * 7;
            f4 a = rp[0];
            #pragma unroll
            for (int i = 1; i < 7; ++i) a += rp[i];
            spool[tid] = (a.x + a.y + a.z + a.w) * (1.0f / 28.0f);
        }
        BLOCK_SYNC();

        // ---- 3. G hidden (0..239) + L conv1 (240..269) ----
        for (int task = tid; task < 270; task += 256) {
            if (task < 240) {
                const int c = task / 20, j = task % 20;
                float acc = 0.f;
                #pragma unroll
                for (int t = 0; t < TT; ++t)
                    acc += spool[c * TT + t] * wg1s[j * TT + t];
                sz[task] = fmaxf(gs[j] * acc + gb[j], 0.f);
            } else {
                const int e = task - 240;
                const int m = e / TT, t = e % TT;
                float acc = 0.f;
                #pragma unroll
                for (int c = 0; c < CC; ++c) {
                    #pragma unroll
                    for (int k = 0; k < 3; ++k) {
                        const int t2 = t + k - 1;
                        if (t2 >= 0 && t2 < TT)
                            acc += spool[c * TT + t2] * wl1s[(m * CC + c) * 3 + k];
                    }
                }
                sa1[e] = fmaxf(lsc[m] * acc + lbi[m], 0.f);
            }
        }
        BLOCK_SYNC();

        // ---- 4. G softmax (12 lanes) + L conv2+sigmoid (120 lanes) ----
        if (tid < CC) {
            const int c = tid;
            float sc0 = 0.f, sc1 = 0.f, sc2 = 0.f;
            #pragma unroll
            for (int j = 0; j < 20; ++j) {
                const float zj = sz[c * 20 + j];
                sc0 += zj * wg2s[j];
                sc1 += zj * wg2s[20 + j];
                sc2 += zj * wg2s[40 + j];
            }
            const float mx = fmaxf(sc0, fmaxf(sc1, sc2));
            const float e0 = __expf(sc0 - mx), e1 = __expf(sc1 - mx), e2 = __expf(sc2 - mx);
            const float ri = 1.0f / (e0 + e1 + e2);
            skern[c]      = e0 * ri;
            skern[12 + c] = e1 * ri;
            skern[24 + c] = e2 * ri;
        }
        if (tid >= 64 && tid < 64 + 120) {
            const int idx = tid - 64;
            const int c = idx / TT, t = idx % TT;
            float acc = 0.f;
            #pragma unroll
            for (int m = 0; m < 3; ++m) acc += sa1[m * TT + t] * wl2s[c * 3 + m];
            sact[idx] = 1.0f / (1.0f + __expf(-acc));
        }
        BLOCK_SYNC();

        // ---- 5. apply: gated 3-tap conv from LDS, transposed NT store ----
        f4* og = reinterpret_cast<f4*>(out + (size_t)n * SAMPLE);
        #pragma unroll
        for (int k = 0; k < 4; ++k) {
            const int v = tid + k * 256;
            if (v < SAMPLE4) {
                const int t   = v / 84;
                const int rem = v % 84;
                const int c   = rem / 7;
                const int s4  = rem % 7;
                const int base = c * 70 + s4;
                const float k0 = skern[c];
                const float k1 = skern[12 + c];
                const float k2 = skern[24 + c];
                f4 acc = (k1 * sact[c * TT + t]) * sx4[base + t * 7];
                if (t > 0)
                    acc += (k0 * sact[c * TT + t - 1]) * sx4[base + (t - 1) * 7];
                if (t < TT - 1)
                    acc += (k2 * sact[c * TT + t + 1]) * sx4[base + (t + 1) * 7];
                __builtin_nontemporal_store(acc, og + v);
            }
        }

        // ---- 6. rotate: all waves done reading sx4, then overwrite with
        //         prefetched regs (compiler emits counted vmcnt here) ----
        BLOCK_SYNC();
        if (pf) {
            #pragma unroll
            for (int k = 0; k < 4; ++k) {
                const int v = tid + k * 256;
                if (v < SAMPLE4) sx4[v] = r[k];
            }
            BLOCK_SYNC();
        }
    }
}

extern "C" void kernel_launch(void* const* d_in, const int* in_sizes, int n_in,
                              void* d_out, int out_size, void* d_ws, size_t ws_size,
                              hipStream_t stream) {
    (void)n_in; (void)out_size; (void)d_ws; (void)ws_size;
    const float* x        = (const float*)d_in[0];
    const float* w_g1     = (const float*)d_in[1];
    const float* g1_gamma = (const float*)d_in[2];
    const float* g1_beta  = (const float*)d_in[3];
    const float* g1_mean  = (const float*)d_in[4];
    const float* g1_var   = (const float*)d_in[5];
    const float* w_g2     = (const float*)d_in[6];
    const float* w_l1     = (const float*)d_in[7];
    const float* l1_gamma = (const float*)d_in[8];
    const float* l1_beta  = (const float*)d_in[9];
    const float* l1_mean  = (const float*)d_in[10];
    const float* l1_var   = (const float*)d_in[11];
    const float* w_l2     = (const float*)d_in[12];
    float* out = (float*)d_out;

    const int n_total = in_sizes[0] / SAMPLE;              // 32768
    const int blocks  = (n_total + SPB - 1) / SPB;         // 4096
    tam_kernel<<<blocks, 256, 0, stream>>>(
        x, w_g1, g1_gamma, g1_beta, g1_mean, g1_var, w_g2,
        w_l1, l1_gamma, l1_beta, l1_mean, l1_var, w_l2, out, n_total);
}